// Round 1
// baseline (570.380 us; speedup 1.0000x reference)
//
#include <hip/hip_runtime.h>

#define HDIM 128

// ---------- degree ----------
__global__ void init_deg_kernel(float* deg, int N) {
    int i = blockIdx.x * blockDim.x + threadIdx.x;
    if (i < N) deg[i] = 1.0f;  // self loop
}

__global__ void count_deg_kernel(const int* __restrict__ col, float* deg, int E) {
    int i = blockIdx.x * blockDim.x + threadIdx.x;
    if (i < E) atomicAdd(&deg[col[i]], 1.0f);
}

__global__ void rsqrt_kernel(float* deg, int N) {
    int i = blockIdx.x * blockDim.x + threadIdx.x;
    if (i < N) deg[i] = rsqrtf(deg[i]);
}

// ---------- GEMM + row scale: xs[n,:] = (X[n,:] @ W) * dinv[n]; also agg init ----------
// X may alias agg (layer 2): each block reads its own rows into LDS before writing.
template<int K, int NPB>
__global__ void gemm_scale_kernel(const float* X, const float* __restrict__ W,
                                  const float* __restrict__ dinv,
                                  float* __restrict__ xs, float* agg, int N) {
    __shared__ float xr[NPB * K];
    int t  = threadIdx.x;            // 128 threads
    int n0 = blockIdx.x * NPB;
    for (int i = t; i < NPB * K; i += 128)
        xr[i] = X[(long)n0 * K + i];
    __syncthreads();

    float acc[NPB];
#pragma unroll
    for (int m = 0; m < NPB; ++m) acc[m] = 0.f;

    for (int k = 0; k < K; ++k) {
        float w = W[k * HDIM + t];
#pragma unroll
        for (int m = 0; m < NPB; ++m) acc[m] += xr[m * K + k] * w;
    }

#pragma unroll
    for (int m = 0; m < NPB; ++m) {
        int n = n0 + m;
        if (n < N) {
            float v = acc[m] * dinv[n];
            xs[(long)n * HDIM + t]  = v;
            agg[(long)n * HDIM + t] = v;   // self-loop init
        }
    }
}

// ---------- edge scatter: agg[c,:] += xs[r,:] ----------
__global__ void scatter_kernel(const int* __restrict__ row, const int* __restrict__ col,
                               const float* __restrict__ xs, float* __restrict__ agg,
                               long total) {
    long stride = (long)gridDim.x * blockDim.x;
    for (long i = (long)blockIdx.x * blockDim.x + threadIdx.x; i < total; i += stride) {
        int e = (int)(i >> 7);
        int d = (int)(i & 127);
        int r = row[e];
        int c = col[e];
        atomicAdd(&agg[(long)c * HDIM + d], xs[(long)r * HDIM + d]);
    }
}

// ---------- finalize: agg = relu(agg*dinv[n] + b[d]) in place ----------
__global__ void finalize_kernel(float* agg, const float* __restrict__ dinv,
                                const float* __restrict__ b, long total) {
    long i = (long)blockIdx.x * blockDim.x + threadIdx.x;
    if (i < total) {
        int n = (int)(i >> 7);
        int d = (int)(i & 127);
        float v = agg[i] * dinv[n] + b[d];
        agg[i] = v > 0.f ? v : 0.f;
    }
}

// ---------- LayerNorm + Q-heads, one wave (64 lanes) per node ----------
__global__ void ln_heads_kernel(const float* __restrict__ h2,
                                const float* __restrict__ lng, const float* __restrict__ lnb,
                                const float* __restrict__ Wq1, const float* __restrict__ bq1,
                                const float* __restrict__ Wq2, const float* __restrict__ bq2,
                                float* __restrict__ q1, float* __restrict__ q2,
                                float* __restrict__ hout, int N) {
    __shared__ float w1s[HDIM * 5];
    __shared__ float w2s[HDIM * 5];
    for (int i = threadIdx.x; i < HDIM * 5; i += blockDim.x) {
        w1s[i] = Wq1[i];
        w2s[i] = Wq2[i];
    }
    __syncthreads();

    int wave = threadIdx.x >> 6;
    int lane = threadIdx.x & 63;
    int node = blockIdx.x * 4 + wave;
    if (node >= N) return;

    const float2* hp = (const float2*)(h2 + (long)node * HDIM);
    float2 v = hp[lane];

    float s  = v.x + v.y;
    float ss = v.x * v.x + v.y * v.y;
#pragma unroll
    for (int off = 32; off >= 1; off >>= 1) {
        s  += __shfl_xor(s, off);
        ss += __shfl_xor(ss, off);
    }
    float mu  = s * (1.0f / HDIM);
    float var = ss * (1.0f / HDIM) - mu * mu;
    float rs  = rsqrtf(var + 1e-5f);

    int d0 = 2 * lane;
    float h0 = (v.x - mu) * rs * lng[d0]     + lnb[d0];
    float h1 = (v.y - mu) * rs * lng[d0 + 1] + lnb[d0 + 1];
    ((float2*)(hout + (long)node * HDIM))[lane] = make_float2(h0, h1);

    float p1[5], p2[5];
#pragma unroll
    for (int j = 0; j < 5; ++j) {
        p1[j] = h0 * w1s[d0 * 5 + j] + h1 * w1s[(d0 + 1) * 5 + j];
        p2[j] = h0 * w2s[d0 * 5 + j] + h1 * w2s[(d0 + 1) * 5 + j];
    }
#pragma unroll
    for (int off = 32; off >= 1; off >>= 1) {
#pragma unroll
        for (int j = 0; j < 5; ++j) {
            p1[j] += __shfl_xor(p1[j], off);
            p2[j] += __shfl_xor(p2[j], off);
        }
    }
    if (lane == 0) {
#pragma unroll
        for (int j = 0; j < 5; ++j) {
            q1[(long)node * 5 + j] = p1[j] + bq1[j];
            q2[(long)node * 5 + j] = p2[j] + bq2[j];
        }
    }
}

extern "C" void kernel_launch(void* const* d_in, const int* in_sizes, int n_in,
                              void* d_out, int out_size, void* d_ws, size_t ws_size,
                              hipStream_t stream) {
    const float* x    = (const float*)d_in[0];
    const int*   ei   = (const int*)d_in[1];
    const float* W1   = (const float*)d_in[2];
    const float* b1   = (const float*)d_in[3];
    const float* W2   = (const float*)d_in[4];
    const float* b2   = (const float*)d_in[5];
    const float* lng  = (const float*)d_in[6];
    const float* lnb  = (const float*)d_in[7];
    const float* Wq1  = (const float*)d_in[8];
    const float* bq1  = (const float*)d_in[9];
    const float* Wq2  = (const float*)d_in[10];
    const float* bq2  = (const float*)d_in[11];

    const int D = 64;
    const int N = in_sizes[0] / D;        // 32768
    const int E = in_sizes[1] / 2;        // 524288
    const int* row = ei;
    const int* col = ei + E;

    float* B0   = (float*)d_ws;                          // N*128 floats
    float* B1   = B0 + (long)N * HDIM;                   // N*128 floats
    float* deg  = B1 + (long)N * HDIM;                   // N floats (deg -> dinv)

    float* q1   = (float*)d_out;
    float* q2   = q1 + (long)N * 5;
    float* hout = q2 + (long)N * 5;

    long totalNH = (long)N * HDIM;
    long totalE  = (long)E * HDIM;

    // degree -> dinv
    init_deg_kernel<<<(N + 255) / 256, 256, 0, stream>>>(deg, N);
    count_deg_kernel<<<(E + 255) / 256, 256, 0, stream>>>(col, deg, E);
    rsqrt_kernel<<<(N + 255) / 256, 256, 0, stream>>>(deg, N);

    // ---- layer 1: xs -> B0, agg -> B1 ----
    gemm_scale_kernel<64, 8><<<(N + 7) / 8, 128, 0, stream>>>(x, W1, deg, B0, B1, N);
    scatter_kernel<<<65536, 256, 0, stream>>>(row, col, B0, B1, totalE);
    finalize_kernel<<<(int)((totalNH + 255) / 256), 256, 0, stream>>>(B1, deg, b1, totalNH);

    // ---- layer 2: X = B1 (h1), xs -> B0, agg -> B1 (in place per-row) ----
    gemm_scale_kernel<128, 8><<<(N + 7) / 8, 128, 0, stream>>>(B1, W2, deg, B0, B1, N);
    scatter_kernel<<<65536, 256, 0, stream>>>(row, col, B0, B1, totalE);
    finalize_kernel<<<(int)((totalNH + 255) / 256), 256, 0, stream>>>(B1, deg, b2, totalNH);

    // ---- LayerNorm + heads ----
    ln_heads_kernel<<<(N + 3) / 4, 256, 0, stream>>>(B1, lng, lnb, Wq1, bq1, Wq2, bq2,
                                                     q1, q2, hout, N);
}

// Round 2
// 317.648 us; speedup vs baseline: 1.7956x; 1.7956x over previous
//
#include <hip/hip_runtime.h>

#define HDIM 128

// ---------- CSR build ----------
__global__ void hist_kernel(const int* __restrict__ col, int* __restrict__ deg, int E) {
    int i = blockIdx.x * blockDim.x + threadIdx.x;
    if (i < E) atomicAdd(&deg[col[i]], 1);
}

// one block, 1024 threads: exclusive scan of deg -> rowptr/cursor, dinv = rsqrt(deg+1)
__global__ __launch_bounds__(1024)
void scan_kernel(const int* __restrict__ deg, int* __restrict__ rowptr,
                 int* __restrict__ cursor, float* __restrict__ dinv, int N) {
    __shared__ int sums[1024];
    int t = threadIdx.x;
    int chunk = (N + 1023) / 1024;
    int s0 = t * chunk;
    int local = 0;
    for (int i = 0; i < chunk; ++i) {
        int idx = s0 + i;
        if (idx < N) local += deg[idx];
    }
    sums[t] = local;
    __syncthreads();
    for (int off = 1; off < 1024; off <<= 1) {
        int v = (t >= off) ? sums[t - off] : 0;
        __syncthreads();
        sums[t] += v;
        __syncthreads();
    }
    int prefix = (t == 0) ? 0 : sums[t - 1];
    for (int i = 0; i < chunk; ++i) {
        int idx = s0 + i;
        if (idx < N) {
            int d = deg[idx];
            rowptr[idx] = prefix;
            cursor[idx] = prefix;
            dinv[idx]   = rsqrtf((float)(d + 1));   // +1 self loop
            prefix += d;
        }
    }
    if (t == 1023) rowptr[N] = prefix;
}

__global__ void fill_kernel(const int* __restrict__ row, const int* __restrict__ col,
                            int* __restrict__ cursor, int* __restrict__ esrc, int E) {
    int i = blockIdx.x * blockDim.x + threadIdx.x;
    if (i < E) {
        int pos = atomicAdd(&cursor[col[i]], 1);
        esrc[pos] = row[i];
    }
}

// ---------- GEMM + row scale: xs[n,:] = (X[n,:] @ W) * dinv[n] ----------
template<int K, int NPB>
__global__ void gemm_scale_kernel(const float* __restrict__ X, const float* __restrict__ W,
                                  const float* __restrict__ dinv,
                                  float* __restrict__ xs, int N) {
    __shared__ float xr[NPB * K];
    int t  = threadIdx.x;            // 128 threads
    int n0 = blockIdx.x * NPB;
    for (int i = t; i < NPB * K; i += 128)
        xr[i] = X[(long)n0 * K + i];
    __syncthreads();

    float acc[NPB];
#pragma unroll
    for (int m = 0; m < NPB; ++m) acc[m] = 0.f;

    for (int k = 0; k < K; ++k) {
        float w = W[k * HDIM + t];
#pragma unroll
        for (int m = 0; m < NPB; ++m) acc[m] += xr[m * K + k] * w;
    }

#pragma unroll
    for (int m = 0; m < NPB; ++m) {
        int n = n0 + m;
        if (n < N) xs[(long)n * HDIM + t] = acc[m] * dinv[n];
    }
}

// ---------- gather: out[c,:] = relu((xs[c,:] + sum_{r->c} xs[r,:]) * dinv[c] + b) ----------
__global__ void gather_kernel(const int* __restrict__ rowptr, const int* __restrict__ esrc,
                              const float* __restrict__ xs, const float* __restrict__ dinv,
                              const float* __restrict__ b, float* __restrict__ out, int N) {
    int d    = threadIdx.x & 127;
    int node = blockIdx.x * 2 + (threadIdx.x >> 7);
    if (node >= N) return;

    float acc = xs[(long)node * HDIM + d];   // self loop (already * dinv[node])
    int s = rowptr[node];
    int e = rowptr[node + 1];
    int j = s;
    for (; j + 4 <= e; j += 4) {
        int r0 = esrc[j];
        int r1 = esrc[j + 1];
        int r2 = esrc[j + 2];
        int r3 = esrc[j + 3];
        float v0 = xs[(long)r0 * HDIM + d];
        float v1 = xs[(long)r1 * HDIM + d];
        float v2 = xs[(long)r2 * HDIM + d];
        float v3 = xs[(long)r3 * HDIM + d];
        acc += (v0 + v1) + (v2 + v3);
    }
    for (; j < e; ++j) acc += xs[(long)esrc[j] * HDIM + d];

    float v = acc * dinv[node] + b[d];
    out[(long)node * HDIM + d] = v > 0.f ? v : 0.f;
}

// ---------- LayerNorm + Q-heads, one wave (64 lanes) per node ----------
__global__ void ln_heads_kernel(const float* __restrict__ h2,
                                const float* __restrict__ lng, const float* __restrict__ lnb,
                                const float* __restrict__ Wq1, const float* __restrict__ bq1,
                                const float* __restrict__ Wq2, const float* __restrict__ bq2,
                                float* __restrict__ q1, float* __restrict__ q2,
                                float* __restrict__ hout, int N) {
    __shared__ float w1s[HDIM * 5];
    __shared__ float w2s[HDIM * 5];
    for (int i = threadIdx.x; i < HDIM * 5; i += blockDim.x) {
        w1s[i] = Wq1[i];
        w2s[i] = Wq2[i];
    }
    __syncthreads();

    int wave = threadIdx.x >> 6;
    int lane = threadIdx.x & 63;
    int node = blockIdx.x * 4 + wave;
    if (node >= N) return;

    const float2* hp = (const float2*)(h2 + (long)node * HDIM);
    float2 v = hp[lane];

    float s  = v.x + v.y;
    float ss = v.x * v.x + v.y * v.y;
#pragma unroll
    for (int off = 32; off >= 1; off >>= 1) {
        s  += __shfl_xor(s, off);
        ss += __shfl_xor(ss, off);
    }
    float mu  = s * (1.0f / HDIM);
    float var = ss * (1.0f / HDIM) - mu * mu;
    float rs  = rsqrtf(var + 1e-5f);

    int d0 = 2 * lane;
    float h0 = (v.x - mu) * rs * lng[d0]     + lnb[d0];
    float h1 = (v.y - mu) * rs * lng[d0 + 1] + lnb[d0 + 1];
    ((float2*)(hout + (long)node * HDIM))[lane] = make_float2(h0, h1);

    float p1[5], p2[5];
#pragma unroll
    for (int j = 0; j < 5; ++j) {
        p1[j] = h0 * w1s[d0 * 5 + j] + h1 * w1s[(d0 + 1) * 5 + j];
        p2[j] = h0 * w2s[d0 * 5 + j] + h1 * w2s[(d0 + 1) * 5 + j];
    }
#pragma unroll
    for (int off = 32; off >= 1; off >>= 1) {
#pragma unroll
        for (int j = 0; j < 5; ++j) {
            p1[j] += __shfl_xor(p1[j], off);
            p2[j] += __shfl_xor(p2[j], off);
        }
    }
    if (lane == 0) {
#pragma unroll
        for (int j = 0; j < 5; ++j) {
            q1[(long)node * 5 + j] = p1[j] + bq1[j];
            q2[(long)node * 5 + j] = p2[j] + bq2[j];
        }
    }
}

extern "C" void kernel_launch(void* const* d_in, const int* in_sizes, int n_in,
                              void* d_out, int out_size, void* d_ws, size_t ws_size,
                              hipStream_t stream) {
    const float* x    = (const float*)d_in[0];
    const int*   ei   = (const int*)d_in[1];
    const float* W1   = (const float*)d_in[2];
    const float* b1   = (const float*)d_in[3];
    const float* W2   = (const float*)d_in[4];
    const float* b2   = (const float*)d_in[5];
    const float* lng  = (const float*)d_in[6];
    const float* lnb  = (const float*)d_in[7];
    const float* Wq1  = (const float*)d_in[8];
    const float* bq1  = (const float*)d_in[9];
    const float* Wq2  = (const float*)d_in[10];
    const float* bq2  = (const float*)d_in[11];

    const int D = 64;
    const int N = in_sizes[0] / D;        // 32768
    const int E = in_sizes[1] / 2;        // 524288
    const int* row = ei;
    const int* col = ei + E;

    // workspace layout
    float* B0     = (float*)d_ws;                 // xs       N*128 f
    float* B1     = B0 + (long)N * HDIM;          // h        N*128 f
    float* dinv   = B1 + (long)N * HDIM;          // N f
    int*   deg    = (int*)(dinv + N);             // N i
    int*   rowptr = deg + N;                      // N+1 i
    int*   cursor = rowptr + N + 1;               // N i
    int*   esrc   = cursor + N;                   // E i

    float* q1   = (float*)d_out;
    float* q2   = q1 + (long)N * 5;
    float* hout = q2 + (long)N * 5;

    // ---- CSR build ----
    hipMemsetAsync(deg, 0, (size_t)N * sizeof(int), stream);
    hist_kernel<<<(E + 255) / 256, 256, 0, stream>>>(col, deg, E);
    scan_kernel<<<1, 1024, 0, stream>>>(deg, rowptr, cursor, dinv, N);
    fill_kernel<<<(E + 255) / 256, 256, 0, stream>>>(row, col, cursor, esrc, E);

    // ---- layer 1 ----
    gemm_scale_kernel<64, 8><<<(N + 7) / 8, 128, 0, stream>>>(x, W1, dinv, B0, N);
    gather_kernel<<<(N + 1) / 2, 256, 0, stream>>>(rowptr, esrc, B0, dinv, b1, B1, N);

    // ---- layer 2 ----
    gemm_scale_kernel<128, 8><<<(N + 7) / 8, 128, 0, stream>>>(B1, W2, dinv, B0, N);
    gather_kernel<<<(N + 1) / 2, 256, 0, stream>>>(rowptr, esrc, B0, dinv, b2, B1, N);

    // ---- LayerNorm + heads ----
    ln_heads_kernel<<<(N + 3) / 4, 256, 0, stream>>>(B1, lng, lnb, Wq1, bq1, Wq2, bq2,
                                                     q1, q2, hout, N);
}

// Round 3
// 228.965 us; speedup vs baseline: 2.4911x; 1.3873x over previous
//
#include <hip/hip_runtime.h>

#define HDIM 128

// ---------- CSR build ----------
__global__ void hist_kernel(const int* __restrict__ col, int* __restrict__ deg, int E) {
    int i = blockIdx.x * blockDim.x + threadIdx.x;
    if (i < E) atomicAdd(&deg[col[i]], 1);
}

// phase A: per-block (256-wide) exclusive scan of deg -> rowptr (partial), block sums
__global__ __launch_bounds__(256)
void scanA_kernel(const int* __restrict__ deg, int* __restrict__ rowptr,
                  int* __restrict__ blocksums, int N) {
    __shared__ int s[256];
    int t = threadIdx.x;
    int i = blockIdx.x * 256 + t;
    int v = (i < N) ? deg[i] : 0;
    s[t] = v;
    __syncthreads();
#pragma unroll
    for (int off = 1; off < 256; off <<= 1) {
        int u = (t >= off) ? s[t - off] : 0;
        __syncthreads();
        s[t] += u;
        __syncthreads();
    }
    if (i < N) rowptr[i] = s[t] - v;           // block-local exclusive
    if (t == 255) blocksums[blockIdx.x] = s[255];
}

// phase B: scan the 128 block sums (one small block)
__global__ __launch_bounds__(128)
void scanB_kernel(int* __restrict__ blocksums, int* __restrict__ rowptr, int N) {
    __shared__ int s[128];
    int t = threadIdx.x;
    int v = blocksums[t];
    s[t] = v;
    __syncthreads();
#pragma unroll
    for (int off = 1; off < 128; off <<= 1) {
        int u = (t >= off) ? s[t - off] : 0;
        __syncthreads();
        s[t] += u;
        __syncthreads();
    }
    blocksums[t] = s[t] - v;                   // exclusive block offsets
    if (t == 127) rowptr[N] = s[127];          // total = E
}

// phase C: add offsets, emit cursor + dinv
__global__ void scanC_kernel(const int* __restrict__ deg, const int* __restrict__ blocksums,
                             int* __restrict__ rowptr, int* __restrict__ cursor,
                             float* __restrict__ dinv, int N) {
    int i = blockIdx.x * blockDim.x + threadIdx.x;
    if (i < N) {
        int p = rowptr[i] + blocksums[i >> 8];
        rowptr[i] = p;
        cursor[i] = p;
        dinv[i]   = rsqrtf((float)(deg[i] + 1));   // +1 self loop
    }
}

__global__ void fill_kernel(const int* __restrict__ row, const int* __restrict__ col,
                            int* __restrict__ cursor, int* __restrict__ esrc, int E) {
    int i = blockIdx.x * blockDim.x + threadIdx.x;
    if (i < E) {
        int pos = atomicAdd(&cursor[col[i]], 1);
        esrc[pos] = row[i];
    }
}

// ---------- GEMM + row scale: xs[n,:] = (X[n,:] @ W) * dinv[n] ----------
template<int K, int NPB>
__global__ void gemm_scale_kernel(const float* __restrict__ X, const float* __restrict__ W,
                                  const float* __restrict__ dinv,
                                  float* __restrict__ xs, int N) {
    __shared__ float xr[NPB * K];
    int t  = threadIdx.x;            // 128 threads
    int n0 = blockIdx.x * NPB;
    for (int i = t; i < NPB * K; i += 128)
        xr[i] = X[(long)n0 * K + i];
    __syncthreads();

    float acc[NPB];
#pragma unroll
    for (int m = 0; m < NPB; ++m) acc[m] = 0.f;

    for (int k = 0; k < K; ++k) {
        float w = W[k * HDIM + t];
#pragma unroll
        for (int m = 0; m < NPB; ++m) acc[m] += xr[m * K + k] * w;
    }

#pragma unroll
    for (int m = 0; m < NPB; ++m) {
        int n = n0 + m;
        if (n < N) xs[(long)n * HDIM + t] = acc[m] * dinv[n];
    }
}

// ---------- gather: out[c,:] = relu((xs[c,:] + sum_{r->c} xs[r,:]) * dinv[c] + b) ----------
__global__ void gather_kernel(const int* __restrict__ rowptr, const int* __restrict__ esrc,
                              const float* __restrict__ xs, const float* __restrict__ dinv,
                              const float* __restrict__ b, float* __restrict__ out, int N) {
    int d    = threadIdx.x & 127;
    int node = blockIdx.x * 2 + (threadIdx.x >> 7);
    if (node >= N) return;

    float acc = xs[(long)node * HDIM + d];   // self loop (already * dinv[node])
    int s = rowptr[node];
    int e = rowptr[node + 1];
    int j = s;
    for (; j + 4 <= e; j += 4) {
        int r0 = esrc[j];
        int r1 = esrc[j + 1];
        int r2 = esrc[j + 2];
        int r3 = esrc[j + 3];
        float v0 = xs[(long)r0 * HDIM + d];
        float v1 = xs[(long)r1 * HDIM + d];
        float v2 = xs[(long)r2 * HDIM + d];
        float v3 = xs[(long)r3 * HDIM + d];
        acc += (v0 + v1) + (v2 + v3);
    }
    for (; j < e; ++j) acc += xs[(long)esrc[j] * HDIM + d];

    float v = acc * dinv[node] + b[d];
    out[(long)node * HDIM + d] = v > 0.f ? v : 0.f;
}

// ---------- LayerNorm + Q-heads, one wave (64 lanes) per node ----------
__global__ void ln_heads_kernel(const float* __restrict__ h2,
                                const float* __restrict__ lng, const float* __restrict__ lnb,
                                const float* __restrict__ Wq1, const float* __restrict__ bq1,
                                const float* __restrict__ Wq2, const float* __restrict__ bq2,
                                float* __restrict__ q1, float* __restrict__ q2,
                                float* __restrict__ hout, int N) {
    __shared__ float w1s[HDIM * 5];
    __shared__ float w2s[HDIM * 5];
    for (int i = threadIdx.x; i < HDIM * 5; i += blockDim.x) {
        w1s[i] = Wq1[i];
        w2s[i] = Wq2[i];
    }
    __syncthreads();

    int wave = threadIdx.x >> 6;
    int lane = threadIdx.x & 63;
    int node = blockIdx.x * 4 + wave;
    if (node >= N) return;

    const float2* hp = (const float2*)(h2 + (long)node * HDIM);
    float2 v = hp[lane];

    float s  = v.x + v.y;
    float ss = v.x * v.x + v.y * v.y;
#pragma unroll
    for (int off = 32; off >= 1; off >>= 1) {
        s  += __shfl_xor(s, off);
        ss += __shfl_xor(ss, off);
    }
    float mu  = s * (1.0f / HDIM);
    float var = ss * (1.0f / HDIM) - mu * mu;
    float rs  = rsqrtf(var + 1e-5f);

    int d0 = 2 * lane;
    float h0 = (v.x - mu) * rs * lng[d0]     + lnb[d0];
    float h1 = (v.y - mu) * rs * lng[d0 + 1] + lnb[d0 + 1];
    ((float2*)(hout + (long)node * HDIM))[lane] = make_float2(h0, h1);

    float p1[5], p2[5];
#pragma unroll
    for (int j = 0; j < 5; ++j) {
        p1[j] = h0 * w1s[d0 * 5 + j] + h1 * w1s[(d0 + 1) * 5 + j];
        p2[j] = h0 * w2s[d0 * 5 + j] + h1 * w2s[(d0 + 1) * 5 + j];
    }
#pragma unroll
    for (int off = 32; off >= 1; off >>= 1) {
#pragma unroll
        for (int j = 0; j < 5; ++j) {
            p1[j] += __shfl_xor(p1[j], off);
            p2[j] += __shfl_xor(p2[j], off);
        }
    }
    if (lane == 0) {
#pragma unroll
        for (int j = 0; j < 5; ++j) {
            q1[(long)node * 5 + j] = p1[j] + bq1[j];
            q2[(long)node * 5 + j] = p2[j] + bq2[j];
        }
    }
}

extern "C" void kernel_launch(void* const* d_in, const int* in_sizes, int n_in,
                              void* d_out, int out_size, void* d_ws, size_t ws_size,
                              hipStream_t stream) {
    const float* x    = (const float*)d_in[0];
    const int*   ei   = (const int*)d_in[1];
    const float* W1   = (const float*)d_in[2];
    const float* b1   = (const float*)d_in[3];
    const float* W2   = (const float*)d_in[4];
    const float* b2   = (const float*)d_in[5];
    const float* lng  = (const float*)d_in[6];
    const float* lnb  = (const float*)d_in[7];
    const float* Wq1  = (const float*)d_in[8];
    const float* bq1  = (const float*)d_in[9];
    const float* Wq2  = (const float*)d_in[10];
    const float* bq2  = (const float*)d_in[11];

    const int D = 64;
    const int N = in_sizes[0] / D;        // 32768
    const int E = in_sizes[1] / 2;        // 524288
    const int* row = ei;
    const int* col = ei + E;

    // workspace layout
    float* B0      = (float*)d_ws;                 // xs       N*128 f
    float* B1      = B0 + (long)N * HDIM;          // h        N*128 f
    float* dinv    = B1 + (long)N * HDIM;          // N f
    int*   deg     = (int*)(dinv + N);             // N i
    int*   rowptr  = deg + N;                      // N+1 i
    int*   cursor  = rowptr + N + 1;               // N i
    int*   esrc    = cursor + N;                   // E i
    int*   bsums   = esrc + E;                     // 128 i

    float* q1   = (float*)d_out;
    float* q2   = q1 + (long)N * 5;
    float* hout = q2 + (long)N * 5;

    const int NB = (N + 255) / 256;       // 128 scan blocks

    // ---- CSR build ----
    hipMemsetAsync(deg, 0, (size_t)N * sizeof(int), stream);
    hist_kernel<<<(E + 255) / 256, 256, 0, stream>>>(col, deg, E);
    scanA_kernel<<<NB, 256, 0, stream>>>(deg, rowptr, bsums, N);
    scanB_kernel<<<1, 128, 0, stream>>>(bsums, rowptr, N);
    scanC_kernel<<<NB, 256, 0, stream>>>(deg, bsums, rowptr, cursor, dinv, N);
    fill_kernel<<<(E + 255) / 256, 256, 0, stream>>>(row, col, cursor, esrc, E);

    // ---- layer 1 ----
    gemm_scale_kernel<64, 8><<<(N + 7) / 8, 128, 0, stream>>>(x, W1, dinv, B0, N);
    gather_kernel<<<(N + 1) / 2, 256, 0, stream>>>(rowptr, esrc, B0, dinv, b1, B1, N);

    // ---- layer 2 ----
    gemm_scale_kernel<128, 8><<<(N + 7) / 8, 128, 0, stream>>>(B1, W2, dinv, B0, N);
    gather_kernel<<<(N + 1) / 2, 256, 0, stream>>>(rowptr, esrc, B0, dinv, b2, B1, N);

    // ---- LayerNorm + heads ----
    ln_heads_kernel<<<(N + 3) / 4, 256, 0, stream>>>(B1, lng, lnb, Wq1, bq1, Wq2, bq2,
                                                     q1, q2, hout, N);
}

// Round 4
// 175.592 us; speedup vs baseline: 3.2483x; 1.3040x over previous
//
#include <hip/hip_runtime.h>

#define HDIM 128

__device__ __forceinline__ ushort f2bf(float f) {
    unsigned x = __float_as_uint(f);
    unsigned r = (x + 0x7fffu + ((x >> 16) & 1u)) >> 16;   // RNE
    return (ushort)r;
}
__device__ __forceinline__ float bf2f(ushort u) {
    return __uint_as_float(((unsigned)u) << 16);
}

// ---------- CSR build ----------
__global__ void zero_kernel(int* __restrict__ p, int n) {
    int i = blockIdx.x * blockDim.x + threadIdx.x;
    if (i < n) p[i] = 0;
}

__global__ void hist_kernel(const int* __restrict__ col, int* __restrict__ deg, int E) {
    int i = blockIdx.x * blockDim.x + threadIdx.x;
    if (i < E) atomicAdd(&deg[col[i]], 1);
}

// phase A: per-block (256-wide) exclusive scan of deg -> rowptr (partial), block sums
__global__ __launch_bounds__(256)
void scanA_kernel(const int* __restrict__ deg, int* __restrict__ rowptr,
                  int* __restrict__ blocksums, int N) {
    __shared__ int s[256];
    int t = threadIdx.x;
    int i = blockIdx.x * 256 + t;
    int v = (i < N) ? deg[i] : 0;
    s[t] = v;
    __syncthreads();
#pragma unroll
    for (int off = 1; off < 256; off <<= 1) {
        int u = (t >= off) ? s[t - off] : 0;
        __syncthreads();
        s[t] += u;
        __syncthreads();
    }
    if (i < N) rowptr[i] = s[t] - v;           // block-local exclusive
    if (t == 255) blocksums[blockIdx.x] = s[255];
}

// phase B: scan the 128 block sums (one small block)
__global__ __launch_bounds__(128)
void scanB_kernel(int* __restrict__ blocksums, int* __restrict__ rowptr, int N) {
    __shared__ int s[128];
    int t = threadIdx.x;
    int v = blocksums[t];
    s[t] = v;
    __syncthreads();
#pragma unroll
    for (int off = 1; off < 128; off <<= 1) {
        int u = (t >= off) ? s[t - off] : 0;
        __syncthreads();
        s[t] += u;
        __syncthreads();
    }
    blocksums[t] = s[t] - v;                   // exclusive block offsets
    if (t == 127) rowptr[N] = s[127];          // total = E
}

// phase C: add offsets, emit cursor + dinv
__global__ void scanC_kernel(const int* __restrict__ deg, const int* __restrict__ blocksums,
                             int* __restrict__ rowptr, int* __restrict__ cursor,
                             float* __restrict__ dinv, int N) {
    int i = blockIdx.x * blockDim.x + threadIdx.x;
    if (i < N) {
        int p = rowptr[i] + blocksums[i >> 8];
        rowptr[i] = p;
        cursor[i] = p;
        dinv[i]   = rsqrtf((float)(deg[i] + 1));   // +1 self loop
    }
}

__global__ void fill_kernel(const int* __restrict__ row, const int* __restrict__ col,
                            int* __restrict__ cursor, int* __restrict__ esrc, int E) {
    int i = blockIdx.x * blockDim.x + threadIdx.x;
    if (i < E) {
        int pos = atomicAdd(&cursor[col[i]], 1);
        esrc[pos] = row[i];
    }
}

// ---------- GEMM + row scale: xs[n,:] = bf16((X[n,:] @ W) * dinv[n]) ----------
template<int K, int NPB>
__global__ void gemm_scale_kernel(const float* __restrict__ X, const float* __restrict__ W,
                                  const float* __restrict__ dinv,
                                  ushort* __restrict__ xs, int N) {
    __shared__ float xr[NPB * K];
    int t  = threadIdx.x;            // 128 threads
    int n0 = blockIdx.x * NPB;
    for (int i = t; i < NPB * K; i += 128)
        xr[i] = X[(long)n0 * K + i];
    __syncthreads();

    float acc[NPB];
#pragma unroll
    for (int m = 0; m < NPB; ++m) acc[m] = 0.f;

    for (int k = 0; k < K; ++k) {
        float w = W[k * HDIM + t];
#pragma unroll
        for (int m = 0; m < NPB; ++m) acc[m] += xr[m * K + k] * w;
    }

#pragma unroll
    for (int m = 0; m < NPB; ++m) {
        int n = n0 + m;
        if (n < N) {
            float v = acc[m] * dinv[n];
            float w = __shfl_xor(v, 1);          // neighbor column's value
            if (!(t & 1)) {
                ushort2 u;
                u.x = f2bf(v);
                u.y = f2bf(w);
                ((ushort2*)xs)[(long)n * 64 + (t >> 1)] = u;
            }
        }
    }
}

// ---------- gather (one wave per node), optionally fused with LN + Q heads ----------
// acc[c,:] = xs[c,:] + sum_{r->c} xs[r,:];  h = relu(acc*dinv[c] + b)
// FUSE_LN: h -> LayerNorm -> hout, q1, q2.   else: h -> out (f32).
template<bool FUSE_LN>
__global__ __launch_bounds__(256)
void gather_kernel(const int* __restrict__ rowptr, const int* __restrict__ esrc,
                   const ushort* __restrict__ xs, const float* __restrict__ dinv,
                   const float* __restrict__ bvec, float* __restrict__ out,
                   const float* __restrict__ lng, const float* __restrict__ lnb,
                   const float* __restrict__ Wq1, const float* __restrict__ bq1,
                   const float* __restrict__ Wq2, const float* __restrict__ bq2,
                   float* __restrict__ q1, float* __restrict__ q2, int N) {
    __shared__ float w1s[FUSE_LN ? HDIM * 5 : 1];
    __shared__ float w2s[FUSE_LN ? HDIM * 5 : 1];
    if (FUSE_LN) {
        for (int i = threadIdx.x; i < HDIM * 5; i += 256) {
            w1s[i] = Wq1[i];
            w2s[i] = Wq2[i];
        }
        __syncthreads();
    }

    int wave = threadIdx.x >> 6;
    int lane = threadIdx.x & 63;
    int node = blockIdx.x * 4 + wave;
    if (node >= N) return;

    const ushort2* rows = (const ushort2*)xs;   // 64 x 4B per row

    ushort2 u = rows[(long)node * 64 + lane];   // self loop
    float ax = bf2f(u.x), ay = bf2f(u.y);

    int s = rowptr[node];
    int e = rowptr[node + 1];
    for (int j = s; j < e; j += 64) {
        int m = e - j;
        if (m > 64) m = 64;
        int idx = (j + lane < e) ? esrc[j + lane] : 0;
        int k = 0;
        for (; k + 4 <= m; k += 4) {
            int r0 = __shfl(idx, k);
            int r1 = __shfl(idx, k + 1);
            int r2 = __shfl(idx, k + 2);
            int r3 = __shfl(idx, k + 3);
            ushort2 u0 = rows[(long)r0 * 64 + lane];
            ushort2 u1 = rows[(long)r1 * 64 + lane];
            ushort2 u2 = rows[(long)r2 * 64 + lane];
            ushort2 u3 = rows[(long)r3 * 64 + lane];
            ax += (bf2f(u0.x) + bf2f(u1.x)) + (bf2f(u2.x) + bf2f(u3.x));
            ay += (bf2f(u0.y) + bf2f(u1.y)) + (bf2f(u2.y) + bf2f(u3.y));
        }
        for (; k < m; ++k) {
            int r = __shfl(idx, k);
            ushort2 uu = rows[(long)r * 64 + lane];
            ax += bf2f(uu.x);
            ay += bf2f(uu.y);
        }
    }

    float di = dinv[node];
    int d0 = 2 * lane;
    float vx = ax * di + bvec[d0];
    float vy = ay * di + bvec[d0 + 1];
    vx = vx > 0.f ? vx : 0.f;
    vy = vy > 0.f ? vy : 0.f;

    if (!FUSE_LN) {
        ((float2*)(out + (long)node * HDIM))[lane] = make_float2(vx, vy);
        return;
    }

    // ---- LayerNorm ----
    float sm = vx + vy, ss = vx * vx + vy * vy;
#pragma unroll
    for (int off = 32; off >= 1; off >>= 1) {
        sm += __shfl_xor(sm, off);
        ss += __shfl_xor(ss, off);
    }
    float mu  = sm * (1.0f / HDIM);
    float var = ss * (1.0f / HDIM) - mu * mu;
    float rs  = rsqrtf(var + 1e-5f);

    float h0 = (vx - mu) * rs * lng[d0]     + lnb[d0];
    float h1 = (vy - mu) * rs * lng[d0 + 1] + lnb[d0 + 1];
    ((float2*)(out + (long)node * HDIM))[lane] = make_float2(h0, h1);

    // ---- Q heads ----
    float p1[5], p2[5];
#pragma unroll
    for (int j = 0; j < 5; ++j) {
        p1[j] = h0 * w1s[d0 * 5 + j] + h1 * w1s[(d0 + 1) * 5 + j];
        p2[j] = h0 * w2s[d0 * 5 + j] + h1 * w2s[(d0 + 1) * 5 + j];
    }
#pragma unroll
    for (int off = 32; off >= 1; off >>= 1) {
#pragma unroll
        for (int j = 0; j < 5; ++j) {
            p1[j] += __shfl_xor(p1[j], off);
            p2[j] += __shfl_xor(p2[j], off);
        }
    }
    if (lane == 0) {
#pragma unroll
        for (int j = 0; j < 5; ++j) {
            q1[(long)node * 5 + j] = p1[j] + bq1[j];
            q2[(long)node * 5 + j] = p2[j] + bq2[j];
        }
    }
}

extern "C" void kernel_launch(void* const* d_in, const int* in_sizes, int n_in,
                              void* d_out, int out_size, void* d_ws, size_t ws_size,
                              hipStream_t stream) {
    const float* x    = (const float*)d_in[0];
    const int*   ei   = (const int*)d_in[1];
    const float* W1   = (const float*)d_in[2];
    const float* b1   = (const float*)d_in[3];
    const float* W2   = (const float*)d_in[4];
    const float* b2   = (const float*)d_in[5];
    const float* lng  = (const float*)d_in[6];
    const float* lnb  = (const float*)d_in[7];
    const float* Wq1  = (const float*)d_in[8];
    const float* bq1  = (const float*)d_in[9];
    const float* Wq2  = (const float*)d_in[10];
    const float* bq2  = (const float*)d_in[11];

    const int D = 64;
    const int N = in_sizes[0] / D;        // 32768
    const int E = in_sizes[1] / 2;        // 524288
    const int* row = ei;
    const int* col = ei + E;

    // workspace layout
    ushort* xs     = (ushort*)d_ws;                   // bf16  N*128
    float*  B1     = (float*)(xs + (long)N * HDIM);   // f32   N*128 (h1)
    float*  dinv   = B1 + (long)N * HDIM;             // N f
    int*    deg    = (int*)(dinv + N);                // N i
    int*    rowptr = deg + N;                         // N+1 i
    int*    cursor = rowptr + N + 1;                  // N i
    int*    esrc   = cursor + N;                      // E i
    int*    bsums  = esrc + E;                        // 128 i

    float* q1   = (float*)d_out;
    float* q2   = q1 + (long)N * 5;
    float* hout = q2 + (long)N * 5;

    const int NB = (N + 255) / 256;       // 128 scan blocks

    // ---- CSR build ----
    zero_kernel<<<NB, 256, 0, stream>>>(deg, N);
    hist_kernel<<<(E + 255) / 256, 256, 0, stream>>>(col, deg, E);
    scanA_kernel<<<NB, 256, 0, stream>>>(deg, rowptr, bsums, N);
    scanB_kernel<<<1, 128, 0, stream>>>(bsums, rowptr, N);
    scanC_kernel<<<NB, 256, 0, stream>>>(deg, bsums, rowptr, cursor, dinv, N);
    fill_kernel<<<(E + 255) / 256, 256, 0, stream>>>(row, col, cursor, esrc, E);

    // ---- layer 1: gemm -> xs(bf16), gather -> B1(f32) ----
    gemm_scale_kernel<64, 8><<<(N + 7) / 8, 128, 0, stream>>>(x, W1, dinv, xs, N);
    gather_kernel<false><<<(N + 3) / 4, 256, 0, stream>>>(
        rowptr, esrc, xs, dinv, b1, B1,
        nullptr, nullptr, nullptr, nullptr, nullptr, nullptr, nullptr, nullptr, N);

    // ---- layer 2: gemm -> xs(bf16), gather fused with LN + heads ----
    gemm_scale_kernel<128, 8><<<(N + 7) / 8, 128, 0, stream>>>(B1, W2, dinv, xs, N);
    gather_kernel<true><<<(N + 3) / 4, 256, 0, stream>>>(
        rowptr, esrc, xs, dinv, b2, hout,
        lng, lnb, Wq1, bq1, Wq2, bq2, q1, q2, N);
}